// Round 2
// baseline (541.445 us; speedup 1.0000x reference)
//
#include <hip/hip_runtime.h>
#include <math.h>

#define NUM_CLASSES 81
#define BATCH 64
#define P 8732
#define M 24
#define THRESH 0.5f

__device__ __forceinline__ float sl1(float d) {
    float a = fabsf(d);
    return a < 1.f ? 0.5f * a * a : a - 0.5f;
}

// ---------------- Kernel 1: matching + loc loss (one block per batch, 1024 thr) ----------------
__global__ __launch_bounds__(1024) void match_kernel(
    const float* __restrict__ loc_data,   // [B,P,4]
    const float* __restrict__ priors,     // [P,4] center-size
    const float* __restrict__ truths,     // [B,M,4] corners
    const int*   __restrict__ labels,     // [B,M]
    int*    __restrict__ conf_t,          // [B,P] out
    int*    __restrict__ num_pos,         // [B] out
    double* __restrict__ loss_l_out)      // [B] out
{
    const int b   = blockIdx.x;
    const int tid = threadIdx.x;
    const int NT  = 1024;
    const int NW  = NT / 64;

    __shared__ float s_truth[M][4];
    __shared__ float s_area[M];
    __shared__ int   s_label[M];
    __shared__ float s_bto[P];            // best_truth_overlap per prior (35KB)
    __shared__ unsigned char s_bti[P];    // best_truth_idx per prior
    __shared__ float s_wbest[NW][M];
    __shared__ int   s_wbidx[NW][M];
    __shared__ int   s_bpi[M];
    __shared__ double s_dl[NW];
    __shared__ int    s_np[NW];

    if (tid < M * 4) ((float*)s_truth)[tid] = truths[b * M * 4 + tid];
    if (tid < M)     s_label[tid] = labels[b * M + tid];
    __syncthreads();
    if (tid < M)
        s_area[tid] = (s_truth[tid][2] - s_truth[tid][0]) * (s_truth[tid][3] - s_truth[tid][1]);
    __syncthreads();

    // per-thread per-truth best (over this thread's priors)
    float tb_val[M];
    int   tb_idx[M];
#pragma unroll
    for (int m = 0; m < M; ++m) { tb_val[m] = -1.0f; tb_idx[m] = 0; }

    for (int p = tid; p < P; p += NT) {
        float4 pr = ((const float4*)priors)[p];
        float bx0 = pr.x - pr.z * 0.5f, by0 = pr.y - pr.w * 0.5f;
        float bx1 = pr.x + pr.z * 0.5f, by1 = pr.y + pr.w * 0.5f;
        float area_b = (bx1 - bx0) * (by1 - by0);
        float best = -1.f; int besti = 0;
#pragma unroll
        for (int m = 0; m < M; ++m) {
            float lx = fmaxf(s_truth[m][0], bx0);
            float ly = fmaxf(s_truth[m][1], by0);
            float rx = fminf(s_truth[m][2], bx1);
            float ry = fminf(s_truth[m][3], by1);
            float w = fmaxf(rx - lx, 0.f), h = fmaxf(ry - ly, 0.f);
            float inter = w * h;
            float iou = inter / (s_area[m] + area_b - inter);
            if (iou > best) { best = iou; besti = m; }          // first m wins
            if (iou > tb_val[m]) { tb_val[m] = iou; tb_idx[m] = p; }  // smallest p wins
        }
        s_bto[p] = best;
        s_bti[p] = (unsigned char)besti;
    }

    // wave-level reduce of per-truth best (prefer larger val, tie -> smaller idx)
#pragma unroll
    for (int m = 0; m < M; ++m) {
        float v = tb_val[m]; int ix = tb_idx[m];
        for (int off = 32; off; off >>= 1) {
            float vo = __shfl_xor(v, off);
            int   io = __shfl_xor(ix, off);
            if (vo > v || (vo == v && io < ix)) { v = vo; ix = io; }
        }
        tb_val[m] = v; tb_idx[m] = ix;
    }
    const int wid = tid >> 6;
    if ((tid & 63) == 0) {
#pragma unroll
        for (int m = 0; m < M; ++m) { s_wbest[wid][m] = tb_val[m]; s_wbidx[wid][m] = tb_idx[m]; }
    }
    __syncthreads();
    if (tid < M) {
        float v = s_wbest[0][tid]; int ix = s_wbidx[0][tid];
        for (int w = 1; w < NW; ++w) {
            float vo = s_wbest[w][tid]; int io = s_wbidx[w][tid];
            if (vo > v || (vo == v && io < ix)) { v = vo; ix = io; }
        }
        s_bpi[tid] = ix;
    }
    __syncthreads();
    // forced matches: sequential, last m wins on collision (numpy scatter semantics)
    if (tid == 0) {
        for (int m = 0; m < M; ++m) {
            int p = s_bpi[m];
            s_bto[p] = 2.0f;
            s_bti[p] = (unsigned char)m;
        }
    }
    __syncthreads();

    // phase B: conf_t, encode, smooth-L1
    double lsum = 0.0;
    int npos = 0;
    for (int p = tid; p < P; p += NT) {
        float ov = s_bto[p];
        int m = (int)s_bti[p];
        int conf = (ov < THRESH) ? 0 : (s_label[m] + 1);
        conf_t[(size_t)b * P + p] = conf;
        if (conf > 0) {
            ++npos;
            float4 pr = ((const float4*)priors)[p];
            float x0 = s_truth[m][0], y0 = s_truth[m][1];
            float x1 = s_truth[m][2], y1 = s_truth[m][3];
            float gcx = ((x0 + x1) * 0.5f - pr.x) / (0.1f * pr.z);
            float gcy = ((y0 + y1) * 0.5f - pr.y) / (0.1f * pr.w);
            float gw  = logf((x1 - x0) / pr.z) / 0.2f;
            float gh  = logf((y1 - y0) / pr.w) / 0.2f;
            float4 ld = ((const float4*)loc_data)[(size_t)b * P + p];
            float s = sl1(ld.x - gcx) + sl1(ld.y - gcy) + sl1(ld.z - gw) + sl1(ld.w - gh);
            lsum += (double)s;
        }
    }
    for (int off = 32; off; off >>= 1) {
        lsum += __shfl_xor(lsum, off);
        npos += __shfl_xor(npos, off);
    }
    if ((tid & 63) == 0) { s_dl[wid] = lsum; s_np[wid] = npos; }
    __syncthreads();
    if (tid == 0) {
        double ls = 0.0; int np = 0;
        for (int w = 0; w < NW; ++w) { ls += s_dl[w]; np += s_np[w]; }
        loss_l_out[b] = ls;
        num_pos[b]    = np;
    }
}

// ---------------- Kernel 2: cross-entropy per prior (16 lanes per row) ----------------
__global__ __launch_bounds__(256) void ce_kernel(
    const float* __restrict__ conf_data,  // [B,P,C]
    int*         __restrict__ conf_t,     // [B,P] read as int, overwritten as float loss_rank
    double*      __restrict__ pos_ce)     // [B] accumulators (pre-zeroed)
{
    const int gl   = threadIdx.x & 15;             // lane in 16-lane group
    const int grp  = threadIdx.x >> 4;             // group within block (0..15)
    const int gpb  = blockDim.x >> 4;              // groups per block
    const int ng   = gpb * gridDim.x;              // total groups
    const int R    = BATCH * P;

    for (int r = blockIdx.x * gpb + grp; r < R; r += ng) {
        const float* x = conf_data + (size_t)r * NUM_CLASSES;
        float v0 = x[gl];
        float v1 = x[gl + 16];
        float v2 = x[gl + 32];
        float v3 = x[gl + 48];
        float v4 = x[gl + 64];
        float v5 = (gl == 0) ? x[80] : -INFINITY;
        float mx = fmaxf(fmaxf(fmaxf(v0, v1), fmaxf(v2, v3)), fmaxf(v4, v5));
#pragma unroll
        for (int off = 8; off; off >>= 1) mx = fmaxf(mx, __shfl_xor(mx, off));
        float se = expf(v0 - mx) + expf(v1 - mx) + expf(v2 - mx) + expf(v3 - mx)
                 + expf(v4 - mx) + ((gl == 0) ? expf(v5 - mx) : 0.f);
#pragma unroll
        for (int off = 8; off; off >>= 1) se += __shfl_xor(se, off);
        int ct = conf_t[r];
        float picked = x[ct];
        float ce = mx + logf(se) - picked;
        if (gl == 0) {
            if (ct > 0) {
                ((float*)conf_t)[r] = 0.0f;                   // positives ranked 0
                atomicAdd(&pos_ce[r / P], (double)ce);
            } else {
                ((float*)conf_t)[r] = ce;                     // nonneg
            }
        }
    }
}

// ---------------- Kernel 3: top-k sum via radix select (one block per batch, 1024 thr) ----------------
__global__ __launch_bounds__(1024) void topk_kernel(
    const float*  __restrict__ loss_rank, // [B,P] nonneg floats
    const int*    __restrict__ num_pos,   // [B]
    const double* __restrict__ pos_ce,    // [B]
    double*       __restrict__ loss_c)    // [B] out
{
    const int b   = blockIdx.x;
    const int tid = threadIdx.x;
    const int NT  = 1024;
    const int NW  = NT / 64;
    __shared__ unsigned int s_key[P];
    __shared__ unsigned int s_hist[256];
    __shared__ unsigned int s_prefix;
    __shared__ int s_rem;
    __shared__ double s_dl[NW];
    __shared__ int    s_ci[NW];

    const unsigned int* src = (const unsigned int*)(loss_rank + (size_t)b * P);
    for (int p = tid; p < P; p += NT) s_key[p] = src[p];
    int k = num_pos[b] * 3;
    if (k > P - 1) k = P - 1;
    __syncthreads();

    unsigned int prefix = 0;
    if (k > 0) {
        int rem = k;
        for (int byte = 3; byte >= 0; --byte) {
            if (tid < 256) s_hist[tid] = 0;
            __syncthreads();
            unsigned int himask = (byte == 3) ? 0u : (0xFFFFFFFFu << ((byte + 1) * 8));
            for (int p = tid; p < P; p += NT) {
                unsigned int key = s_key[p];
                if ((key & himask) == prefix)
                    atomicAdd(&s_hist[(key >> (byte * 8)) & 255u], 1u);
            }
            __syncthreads();
            if (tid == 0) {
                int cum = 0, chosen = 0;
                for (int bk = 255; bk >= 0; --bk) {
                    int c = (int)s_hist[bk];
                    if (cum + c >= rem) { chosen = bk; break; }
                    cum += c;
                }
                s_prefix = prefix | ((unsigned)chosen << (byte * 8));
                s_rem = rem - cum;
            }
            __syncthreads();
            prefix = s_prefix;
            rem    = s_rem;
        }
    }

    // sum of values strictly greater than T, plus (k - cnt) copies of T
    double sum_gt = 0.0;
    int    cnt_gt = 0;
    if (k > 0) {
        for (int p = tid; p < P; p += NT) {
            unsigned int key = s_key[p];
            if (key > prefix) { sum_gt += (double)__uint_as_float(key); ++cnt_gt; }
        }
    }
    for (int off = 32; off; off >>= 1) {
        sum_gt += __shfl_xor(sum_gt, off);
        cnt_gt += __shfl_xor(cnt_gt, off);
    }
    const int wid = tid >> 6;
    if ((tid & 63) == 0) { s_dl[wid] = sum_gt; s_ci[wid] = cnt_gt; }
    __syncthreads();
    if (tid == 0) {
        double sg = 0.0; int cg = 0;
        for (int w = 0; w < NW; ++w) { sg += s_dl[w]; cg += s_ci[w]; }
        double tk = 0.0;
        if (k > 0) tk = sg + (double)(k - cg) * (double)__uint_as_float(prefix);
        loss_c[b] = pos_ce[b] + tk;
    }
}

// ---------------- Kernel 4: final reduction ----------------
__global__ void final_kernel(const double* __restrict__ loss_l,
                             const double* __restrict__ loss_c,
                             const int*    __restrict__ num_pos,
                             float* __restrict__ out)
{
    int t = threadIdx.x; // 64 threads
    double ll = loss_l[t];
    double lc = loss_c[t];
    int    n  = num_pos[t];
    for (int off = 32; off; off >>= 1) {
        ll += __shfl_xor(ll, off);
        lc += __shfl_xor(lc, off);
        n  += __shfl_xor(n, off);
    }
    if (t == 0) {
        double N = (double)n;
        out[0] = (float)(ll / N);
        out[1] = (float)(lc / N);
    }
}

extern "C" void kernel_launch(void* const* d_in, const int* in_sizes, int n_in,
                              void* d_out, int out_size, void* d_ws, size_t ws_size,
                              hipStream_t stream)
{
    const float* loc_data  = (const float*)d_in[0];
    const float* conf_data = (const float*)d_in[1];
    const float* priors    = (const float*)d_in[2];
    const float* truths    = (const float*)d_in[3];
    const int*   labels    = (const int*)d_in[4];
    float* out = (float*)d_out;

    char* ws = (char*)d_ws;
    int* conf_t = (int*)ws;                                  // B*P ints, later reused as float loss_rank
    size_t off = (size_t)BATCH * P * sizeof(int);
    off = (off + 7) & ~(size_t)7;
    int* num_pos = (int*)(ws + off);     off += 64 * sizeof(int);
    off = (off + 7) & ~(size_t)7;
    double* loss_l = (double*)(ws + off); off += 64 * sizeof(double);
    double* pos_ce = (double*)(ws + off); off += 64 * sizeof(double);
    double* loss_c = (double*)(ws + off); off += 64 * sizeof(double);

    hipMemsetAsync(pos_ce, 0, 64 * sizeof(double), stream);

    match_kernel<<<BATCH, 1024, 0, stream>>>(loc_data, priors, truths, labels,
                                             conf_t, num_pos, loss_l);
    ce_kernel<<<2048, 256, 0, stream>>>(conf_data, conf_t, pos_ce);
    topk_kernel<<<BATCH, 1024, 0, stream>>>((const float*)conf_t, num_pos, pos_ce, loss_c);
    final_kernel<<<1, 64, 0, stream>>>(loss_l, loss_c, num_pos, out);
}

// Round 3
// 356.267 us; speedup vs baseline: 1.5198x; 1.5198x over previous
//
#include <hip/hip_runtime.h>
#include <math.h>

#define NUM_CLASSES 81
#define BATCH 64
#define P 8732
#define M 24
#define THRESH 0.5f

__device__ __forceinline__ float sl1f(float d) {
    float a = fabsf(d);
    return a < 1.f ? 0.5f * a * a : a - 0.5f;
}

__device__ __forceinline__ unsigned long long packkey(float v, int p) {
    return ((unsigned long long)__float_as_uint(v) << 32)
         | (unsigned long long)(0xFFFFFFFFu - (unsigned)p);
}

// ---------- Kernel A: per-prior match, per-truth best via packed atomicMax ----------
__global__ __launch_bounds__(256) void prior_match_kernel(
    const float* __restrict__ priors,   // [P,4] center-size
    const float* __restrict__ truths,   // [B,M,4] corners
    const int*   __restrict__ labels,   // [B,M]
    unsigned short* __restrict__ cmb,   // [B,P] conf | (bti<<8)
    unsigned long long* __restrict__ bpk) // [B,M] packed (iou, ~p), pre-zeroed
{
    const int b   = blockIdx.y;
    const int tid = threadIdx.x;
    const int p   = blockIdx.x * 256 + tid;
    const int wid = tid >> 6;

    __shared__ float s_truth[M][4];
    __shared__ float s_area[M];
    __shared__ int   s_label[M];
    __shared__ float s_v[4][M];
    __shared__ int   s_ix[4][M];

    if (tid < M * 4) ((float*)s_truth)[tid] = truths[b * M * 4 + tid];
    if (tid < M)     s_label[tid] = labels[b * M + tid];
    __syncthreads();
    if (tid < M)
        s_area[tid] = (s_truth[tid][2] - s_truth[tid][0]) * (s_truth[tid][3] - s_truth[tid][1]);
    __syncthreads();

    const int pc = (p < P) ? p : 0;
    float4 pr = ((const float4*)priors)[pc];
    float bx0 = pr.x - pr.z * 0.5f, by0 = pr.y - pr.w * 0.5f;
    float bx1 = pr.x + pr.z * 0.5f, by1 = pr.y + pr.w * 0.5f;
    float area_b = (bx1 - bx0) * (by1 - by0);

    float best = -1.f; int besti = 0;
    for (int m = 0; m < M; ++m) {
        float lx = fmaxf(s_truth[m][0], bx0);
        float ly = fmaxf(s_truth[m][1], by0);
        float rx = fminf(s_truth[m][2], bx1);
        float ry = fminf(s_truth[m][3], by1);
        float w = fmaxf(rx - lx, 0.f), h = fmaxf(ry - ly, 0.f);
        float inter = w * h;
        float iou = inter / (s_area[m] + area_b - inter);
        if (p < P && iou > best) { best = iou; besti = m; }   // first m wins ties
        // wave reduce (max iou, tie -> smaller p)
        float v = (p < P) ? iou : -1.f;
        int ix = p;
        for (int off = 32; off; off >>= 1) {
            float vo = __shfl_xor(v, off);
            int   io = __shfl_xor(ix, off);
            if (vo > v || (vo == v && io < ix)) { v = vo; ix = io; }
        }
        if ((tid & 63) == 0) { s_v[wid][m] = v; s_ix[wid][m] = ix; }
    }
    __syncthreads();
    if (tid < M) {
        float v = s_v[0][tid]; int ix = s_ix[0][tid];
        for (int w = 1; w < 4; ++w) {
            float vo = s_v[w][tid]; int io = s_ix[w][tid];
            if (vo > v || (vo == v && io < ix)) { v = vo; ix = io; }
        }
        if (v >= 0.f)
            atomicMax(&bpk[b * M + tid], packkey(v, ix));
    }
    if (p < P) {
        int conf = (best < THRESH) ? 0 : (s_label[besti] + 1);
        cmb[(size_t)b * P + p] = (unsigned short)(conf | (besti << 8));
    }
}

// ---------- Kernel B: forced matches (last m wins on duplicate prior) ----------
__global__ __launch_bounds__(64) void force_match_kernel(
    const unsigned long long* __restrict__ bpk,
    const int* __restrict__ labels,
    unsigned short* __restrict__ cmb)
{
    const int b   = blockIdx.x;
    const int tid = threadIdx.x;
    unsigned int pm = 0xFFFFFFFFu;
    if (tid < M)
        pm = 0xFFFFFFFFu - (unsigned)(bpk[b * M + tid] & 0xFFFFFFFFull);
    bool dead = false;
    for (int m2 = 1; m2 < M; ++m2) {
        unsigned int p2 = __shfl(pm, m2);
        if (tid < m2 && p2 == pm) dead = true;   // a later m claims same prior
    }
    if (tid < M && !dead)
        cmb[(size_t)b * P + pm] =
            (unsigned short)((labels[b * M + tid] + 1) | (tid << 8));
}

// ---------- Kernel C: fused CE + loc loss + num_pos (16 lanes per row) ----------
__global__ __launch_bounds__(256) void ce_kernel(
    const float* __restrict__ conf_data,  // [B,P,C]
    const float* __restrict__ loc_data,   // [B,P,4]
    const float* __restrict__ priors,     // [P,4]
    const float* __restrict__ truths,     // [B,M,4]
    const unsigned short* __restrict__ cmb,
    float*  __restrict__ loss_rank,       // [B,P] out
    double* __restrict__ loss_l,          // [B] accum (pre-zeroed)
    double* __restrict__ pos_ce,          // [B] accum (pre-zeroed)
    int*    __restrict__ num_pos)         // [B] accum (pre-zeroed)
{
    const int b   = blockIdx.y;
    const int gl  = threadIdx.x & 15;
    const int grp = threadIdx.x >> 4;
    const int p   = blockIdx.x * 16 + grp;
    const int wid = threadIdx.x >> 6;

    __shared__ double s_dl[4], s_dc[4];
    __shared__ int    s_np[4];

    double lsum = 0.0, csum = 0.0;
    int np = 0;

    if (p < P) {
        const float* x = conf_data + ((size_t)b * P + p) * NUM_CLASSES;
        float4 v4 = *(const float4*)(x + gl * 4);   // classes 0..63
        float v64 = x[64 + gl];                     // classes 64..79
        float v80 = -1e30f;
        float mx = fmaxf(fmaxf(v4.x, v4.y), fmaxf(v4.z, v4.w));
        mx = fmaxf(mx, v64);
        if (gl == 0) { v80 = x[80]; mx = fmaxf(mx, v80); }
#pragma unroll
        for (int off = 8; off; off >>= 1) mx = fmaxf(mx, __shfl_xor(mx, off));
        float se = __expf(v4.x - mx) + __expf(v4.y - mx) + __expf(v4.z - mx)
                 + __expf(v4.w - mx) + __expf(v64 - mx);
        if (gl == 0) se += __expf(v80 - mx);
#pragma unroll
        for (int off = 8; off; off >>= 1) se += __shfl_xor(se, off);

        if (gl == 0) {
            unsigned int cm = cmb[(size_t)b * P + p];
            int conf = cm & 0xFF, mt = cm >> 8;
            float ce = mx + __logf(se) - x[conf];
            if (conf > 0) {
                loss_rank[(size_t)b * P + p] = 0.f;   // positives ranked 0
                csum = (double)ce; np = 1;
                float4 t   = ((const float4*)truths)[b * M + mt];
                float4 prr = ((const float4*)priors)[p];
                float4 ld  = ((const float4*)loc_data)[(size_t)b * P + p];
                float gcx = ((t.x + t.z) * 0.5f - prr.x) / (0.1f * prr.z);
                float gcy = ((t.y + t.w) * 0.5f - prr.y) / (0.1f * prr.w);
                float gw  = logf((t.z - t.x) / prr.z) / 0.2f;
                float gh  = logf((t.w - t.y) / prr.w) / 0.2f;
                lsum = (double)(sl1f(ld.x - gcx) + sl1f(ld.y - gcy)
                              + sl1f(ld.z - gw) + sl1f(ld.w - gh));
            } else {
                loss_rank[(size_t)b * P + p] = ce;    // nonneg
            }
        }
    }
    // block reduce (idle lanes contribute zeros)
#pragma unroll
    for (int off = 32; off; off >>= 1) {
        lsum += __shfl_xor(lsum, off);
        csum += __shfl_xor(csum, off);
        np   += __shfl_xor(np, off);
    }
    if ((threadIdx.x & 63) == 0) { s_dl[wid] = lsum; s_dc[wid] = csum; s_np[wid] = np; }
    __syncthreads();
    if (threadIdx.x == 0) {
        double tl = s_dl[0] + s_dl[1] + s_dl[2] + s_dl[3];
        double tc = s_dc[0] + s_dc[1] + s_dc[2] + s_dc[3];
        int    tn = s_np[0] + s_np[1] + s_np[2] + s_np[3];
        if (tn > 0) {
            atomicAdd(&loss_l[b], tl);
            atomicAdd(&pos_ce[b], tc);
            atomicAdd(&num_pos[b], tn);
        }
    }
}

// ---------- Kernel D: top-k sum via radix select (one block per batch) ----------
__global__ __launch_bounds__(1024) void topk_kernel(
    const float*  __restrict__ loss_rank, // [B,P] nonneg floats
    const int*    __restrict__ num_pos,   // [B]
    const double* __restrict__ pos_ce,    // [B]
    double*       __restrict__ loss_c)    // [B] out
{
    const int b   = blockIdx.x;
    const int tid = threadIdx.x;
    const int NT  = 1024;
    const int NW  = NT / 64;
    __shared__ unsigned int s_key[P];
    __shared__ unsigned int s_hist[256];
    __shared__ unsigned int s_prefix;
    __shared__ int s_rem;
    __shared__ double s_dl[NW];
    __shared__ int    s_ci[NW];

    const unsigned int* src = (const unsigned int*)(loss_rank + (size_t)b * P);
    for (int p = tid; p < P; p += NT) s_key[p] = src[p];
    int k = num_pos[b] * 3;
    if (k > P - 1) k = P - 1;
    __syncthreads();

    unsigned int prefix = 0;
    if (k > 0) {
        int rem = k;
        for (int byte = 3; byte >= 0; --byte) {
            if (tid < 256) s_hist[tid] = 0;
            __syncthreads();
            unsigned int himask = (byte == 3) ? 0u : (0xFFFFFFFFu << ((byte + 1) * 8));
            for (int p = tid; p < P; p += NT) {
                unsigned int key = s_key[p];
                if ((key & himask) == prefix)
                    atomicAdd(&s_hist[(key >> (byte * 8)) & 255u], 1u);
            }
            __syncthreads();
            if (tid == 0) {
                int cum = 0, chosen = 0;
                for (int bk = 255; bk >= 0; --bk) {
                    int c = (int)s_hist[bk];
                    if (cum + c >= rem) { chosen = bk; break; }
                    cum += c;
                }
                s_prefix = prefix | ((unsigned)chosen << (byte * 8));
                s_rem = rem - cum;
            }
            __syncthreads();
            prefix = s_prefix;
            rem    = s_rem;
        }
    }

    double sum_gt = 0.0;
    int    cnt_gt = 0;
    if (k > 0) {
        for (int p = tid; p < P; p += NT) {
            unsigned int key = s_key[p];
            if (key > prefix) { sum_gt += (double)__uint_as_float(key); ++cnt_gt; }
        }
    }
    for (int off = 32; off; off >>= 1) {
        sum_gt += __shfl_xor(sum_gt, off);
        cnt_gt += __shfl_xor(cnt_gt, off);
    }
    const int wid = tid >> 6;
    if ((tid & 63) == 0) { s_dl[wid] = sum_gt; s_ci[wid] = cnt_gt; }
    __syncthreads();
    if (tid == 0) {
        double sg = 0.0; int cg = 0;
        for (int w = 0; w < NW; ++w) { sg += s_dl[w]; cg += s_ci[w]; }
        double tk = 0.0;
        if (k > 0) tk = sg + (double)(k - cg) * (double)__uint_as_float(prefix);
        loss_c[b] = pos_ce[b] + tk;
    }
}

// ---------- Kernel E: final reduction ----------
__global__ void final_kernel(const double* __restrict__ loss_l,
                             const double* __restrict__ loss_c,
                             const int*    __restrict__ num_pos,
                             float* __restrict__ out)
{
    int t = threadIdx.x; // 64 threads
    double ll = loss_l[t];
    double lc = loss_c[t];
    int    n  = num_pos[t];
    for (int off = 32; off; off >>= 1) {
        ll += __shfl_xor(ll, off);
        lc += __shfl_xor(lc, off);
        n  += __shfl_xor(n, off);
    }
    if (t == 0) {
        double N = (double)n;
        out[0] = (float)(ll / N);
        out[1] = (float)(lc / N);
    }
}

extern "C" void kernel_launch(void* const* d_in, const int* in_sizes, int n_in,
                              void* d_out, int out_size, void* d_ws, size_t ws_size,
                              hipStream_t stream)
{
    const float* loc_data  = (const float*)d_in[0];
    const float* conf_data = (const float*)d_in[1];
    const float* priors    = (const float*)d_in[2];
    const float* truths    = (const float*)d_in[3];
    const int*   labels    = (const int*)d_in[4];
    float* out = (float*)d_out;

    char* ws = (char*)d_ws;
    size_t off = 0;
    float* loss_rank = (float*)(ws + off);           off += (size_t)BATCH * P * 4;
    unsigned short* cmb = (unsigned short*)(ws + off); off += (size_t)BATCH * P * 2;
    off = (off + 15) & ~(size_t)15;
    unsigned long long* bpk = (unsigned long long*)(ws + off); off += (size_t)BATCH * M * 8;
    int*    num_pos = (int*)(ws + off);    off += 64 * sizeof(int);
    double* loss_l  = (double*)(ws + off); off += 64 * sizeof(double);
    double* pos_ce  = (double*)(ws + off); off += 64 * sizeof(double);
    double* loss_c  = (double*)(ws + off); off += 64 * sizeof(double);

    // zero bpk + num_pos + loss_l + pos_ce in one async memset (contiguous)
    hipMemsetAsync(bpk, 0,
                   (size_t)BATCH * M * 8 + 64 * sizeof(int) + 2 * 64 * sizeof(double),
                   stream);

    dim3 gA((P + 255) / 256, BATCH);
    prior_match_kernel<<<gA, 256, 0, stream>>>(priors, truths, labels, cmb, bpk);
    force_match_kernel<<<BATCH, 64, 0, stream>>>(bpk, labels, cmb);
    dim3 gC((P + 15) / 16, BATCH);
    ce_kernel<<<gC, 256, 0, stream>>>(conf_data, loc_data, priors, truths, cmb,
                                      loss_rank, loss_l, pos_ce, num_pos);
    topk_kernel<<<BATCH, 1024, 0, stream>>>(loss_rank, num_pos, pos_ce, loss_c);
    final_kernel<<<1, 64, 0, stream>>>(loss_l, loss_c, num_pos, out);
}

// Round 4
// 160.819 us; speedup vs baseline: 3.3668x; 2.2153x over previous
//
#include <hip/hip_runtime.h>
#include <math.h>

#define NUM_CLASSES 81
#define BATCH 64
#define P 8732
#define M 24
#define THRESH 0.5f
#define R_TOTAL (BATCH * P)          // 558848
#define RPB 64                       // rows per block in stream kernel
#define LDS_PITCH 85                 // padded row pitch (dwords)

__device__ __forceinline__ float sl1f(float d) {
    float a = fabsf(d);
    return a < 1.f ? 0.5f * a * a : a - 0.5f;
}

__device__ __forceinline__ unsigned long long packkey(float v, int p) {
    return ((unsigned long long)__float_as_uint(v) << 32)
         | (unsigned long long)(0xFFFFFFFFu - (unsigned)p);
}

// ---------- Kernel A: per-prior match, per-truth best via packed atomicMax ----------
__global__ __launch_bounds__(256) void prior_match_kernel(
    const float* __restrict__ priors,   // [P,4] center-size
    const float* __restrict__ truths,   // [B,M,4] corners
    const int*   __restrict__ labels,   // [B,M]
    unsigned short* __restrict__ cmb,   // [B,P] conf | (bti<<8)
    unsigned long long* __restrict__ bpk) // [B,M] packed (iou, ~p), pre-zeroed
{
    const int b   = blockIdx.y;
    const int tid = threadIdx.x;
    const int p   = blockIdx.x * 256 + tid;
    const int wid = tid >> 6;

    __shared__ float s_truth[M][4];
    __shared__ float s_area[M];
    __shared__ int   s_label[M];
    __shared__ float s_v[4][M];
    __shared__ int   s_ix[4][M];

    if (tid < M * 4) ((float*)s_truth)[tid] = truths[b * M * 4 + tid];
    if (tid < M)     s_label[tid] = labels[b * M + tid];
    __syncthreads();
    if (tid < M)
        s_area[tid] = (s_truth[tid][2] - s_truth[tid][0]) * (s_truth[tid][3] - s_truth[tid][1]);
    __syncthreads();

    const int pc = (p < P) ? p : 0;
    float4 pr = ((const float4*)priors)[pc];
    float bx0 = pr.x - pr.z * 0.5f, by0 = pr.y - pr.w * 0.5f;
    float bx1 = pr.x + pr.z * 0.5f, by1 = pr.y + pr.w * 0.5f;
    float area_b = (bx1 - bx0) * (by1 - by0);

    float best = -1.f; int besti = 0;
    for (int m = 0; m < M; ++m) {
        float lx = fmaxf(s_truth[m][0], bx0);
        float ly = fmaxf(s_truth[m][1], by0);
        float rx = fminf(s_truth[m][2], bx1);
        float ry = fminf(s_truth[m][3], by1);
        float w = fmaxf(rx - lx, 0.f), h = fmaxf(ry - ly, 0.f);
        float inter = w * h;
        float iou = inter / (s_area[m] + area_b - inter);
        if (p < P && iou > best) { best = iou; besti = m; }   // first m wins ties
        // wave reduce (max iou, tie -> smaller p)
        float v = (p < P) ? iou : -1.f;
        int ix = p;
        for (int off = 32; off; off >>= 1) {
            float vo = __shfl_xor(v, off);
            int   io = __shfl_xor(ix, off);
            if (vo > v || (vo == v && io < ix)) { v = vo; ix = io; }
        }
        if ((tid & 63) == 0) { s_v[wid][m] = v; s_ix[wid][m] = ix; }
    }
    __syncthreads();
    if (tid < M) {
        float v = s_v[0][tid]; int ix = s_ix[0][tid];
        for (int w = 1; w < 4; ++w) {
            float vo = s_v[w][tid]; int io = s_ix[w][tid];
            if (vo > v || (vo == v && io < ix)) { v = vo; ix = io; }
        }
        if (v >= 0.f)
            atomicMax(&bpk[b * M + tid], packkey(v, ix));
    }
    if (p < P) {
        int conf = (best < THRESH) ? 0 : (s_label[besti] + 1);
        cmb[(size_t)b * P + p] = (unsigned short)(conf | (besti << 8));
    }
}

// ---------- Kernel B: forced matches (last m wins on duplicate prior) ----------
__global__ __launch_bounds__(64) void force_match_kernel(
    const unsigned long long* __restrict__ bpk,
    const int* __restrict__ labels,
    unsigned short* __restrict__ cmb)
{
    const int b   = blockIdx.x;
    const int tid = threadIdx.x;
    unsigned int pm = 0xFFFFFFFFu;
    if (tid < M)
        pm = 0xFFFFFFFFu - (unsigned)(bpk[b * M + tid] & 0xFFFFFFFFull);
    bool dead = false;
    for (int m2 = 1; m2 < M; ++m2) {
        unsigned int p2 = __shfl(pm, m2);
        if (tid < m2 && p2 == pm) dead = true;   // a later m claims same prior
    }
    if (tid < M && !dead)
        cmb[(size_t)b * P + pm] =
            (unsigned short)((labels[b * M + tid] + 1) | (tid << 8));
}

// ---------- Kernel C1: pure-stream logsumexp - x[0] ----------
// block = 256 thr handles 64 rows = 20736 B, block base 16B-aligned.
__global__ __launch_bounds__(256) void stream_lse_kernel(
    const float* __restrict__ conf_data,  // [B*P, 81]
    float* __restrict__ loss_rank)        // [B*P] out: lse - x[0]
{
    const int tid = threadIdx.x;
    __shared__ float s[RPB * LDS_PITCH];  // 64*85 dwords = 21760 B

    const size_t gbase = (size_t)blockIdx.x * (RPB * NUM_CLASSES); // dwords
    const float4* src4 = (const float4*)(conf_data + gbase);       // 16B-aligned

    // stage 1296 float4 (5184 dwords), de-padded into 85-pitch rows
    for (int f = tid; f < (RPB * NUM_CLASSES) / 4; f += 256) {
        float4 v = src4[f];
        int d = 4 * f;
#pragma unroll
        for (int j = 0; j < 4; ++j) {
            int dj  = d + j;
            int row = (unsigned)dj / NUM_CLASSES;
            int col = dj - row * NUM_CLASSES;
            s[row * LDS_PITCH + col] = ((const float*)&v)[j];
        }
    }
    __syncthreads();

    const int rq = tid >> 2;        // row 0..63
    const int l  = tid & 3;         // quad lane
    const float* srow = s + rq * LDS_PITCH;
    float a0 = 0.f, a1 = 0.f, a2 = 0.f, a3 = 0.f;
#pragma unroll
    for (int j = 0; j < 20; j += 4) {
        a0 += __expf(srow[l * 20 + j]);
        a1 += __expf(srow[l * 20 + j + 1]);
        a2 += __expf(srow[l * 20 + j + 2]);
        a3 += __expf(srow[l * 20 + j + 3]);
    }
    float sum = (a0 + a1) + (a2 + a3);
    sum += __shfl_xor(sum, 1);
    sum += __shfl_xor(sum, 2);
    if (l == 0) {
        float se = sum + __expf(srow[80]);
        loss_rank[blockIdx.x * RPB + rq] = __logf(se) - srow[0];
    }
}

// ---------- Kernel C2: sparse positive fixup ----------
__global__ __launch_bounds__(256) void fixup_kernel(
    const float* __restrict__ conf_data,
    const float* __restrict__ loc_data,
    const float* __restrict__ priors,
    const float* __restrict__ truths,
    const unsigned short* __restrict__ cmb,
    float*  __restrict__ loss_rank,
    double* __restrict__ loss_l,
    double* __restrict__ pos_ce,
    int*    __restrict__ num_pos)
{
    const int r    = blockIdx.x * 256 + threadIdx.x;   // grid sized exactly
    const int lane = threadIdx.x & 63;
    const int b    = (unsigned)r / P;
    const int p    = r - b * P;

    unsigned cm = cmb[r];
    int conf = cm & 0xFF;
    float ll = 0.f, ce = 0.f;
    int np = 0;
    if (conf > 0) {
        int mt = cm >> 8;
        const float* x = conf_data + (size_t)r * NUM_CLASSES;
        float lr = loss_rank[r];
        ce = lr + x[0] - x[conf];
        loss_rank[r] = 0.f;
        np = 1;
        float4 t  = ((const float4*)truths)[b * M + mt];
        float4 pr = ((const float4*)priors)[p];
        float4 ld = ((const float4*)loc_data)[r];
        float gcx = ((t.x + t.z) * 0.5f - pr.x) / (0.1f * pr.z);
        float gcy = ((t.y + t.w) * 0.5f - pr.y) / (0.1f * pr.w);
        float gw  = logf((t.z - t.x) / pr.z) / 0.2f;
        float gh  = logf((t.w - t.y) / pr.w) / 0.2f;
        ll = sl1f(ld.x - gcx) + sl1f(ld.y - gcy) + sl1f(ld.z - gw) + sl1f(ld.w - gh);
    }

    int b0 = __shfl(b, 0);
    bool uni = __all(b == b0);
    if (uni) {
#pragma unroll
        for (int off = 32; off; off >>= 1) {
            ll += __shfl_xor(ll, off);
            ce += __shfl_xor(ce, off);
            np += __shfl_xor(np, off);
        }
        if (lane == 0 && np > 0) {
            atomicAdd(&loss_l[b0], (double)ll);
            atomicAdd(&pos_ce[b0], (double)ce);
            atomicAdd(&num_pos[b0], np);
        }
    } else if (conf > 0) {
        atomicAdd(&loss_l[b], (double)ll);
        atomicAdd(&pos_ce[b], (double)ce);
        atomicAdd(&num_pos[b], np);
    }
}

// ---------- Kernel D: top-k sum via radix select (parallel bucket scan) ----------
__global__ __launch_bounds__(1024) void topk_kernel(
    const float*  __restrict__ loss_rank, // [B,P] nonneg floats
    const int*    __restrict__ num_pos,   // [B]
    const double* __restrict__ pos_ce,    // [B]
    double*       __restrict__ loss_c)    // [B] out
{
    const int b   = blockIdx.x;
    const int tid = threadIdx.x;
    const int NT  = 1024;
    const int NW  = NT / 64;
    __shared__ unsigned int s_key[P];
    __shared__ unsigned int s_hist[256];
    __shared__ unsigned int s_suf[256];
    __shared__ unsigned int s_wtot[4];
    __shared__ unsigned int s_prefix;
    __shared__ int s_rem;
    __shared__ double s_dl[NW];
    __shared__ int    s_ci[NW];

    const unsigned int* src = (const unsigned int*)(loss_rank + (size_t)b * P);
    for (int p = tid; p < P; p += NT) s_key[p] = src[p];
    int k = num_pos[b] * 3;
    if (k > P - 1) k = P - 1;
    __syncthreads();

    unsigned int prefix = 0;
    if (k > 0) {
        int rem = k;
        for (int byte = 3; byte >= 0; --byte) {
            if (tid < 256) s_hist[tid] = 0;
            __syncthreads();
            unsigned int himask = (byte == 3) ? 0u : (0xFFFFFFFFu << ((byte + 1) * 8));
            for (int p = tid; p < P; p += NT) {
                unsigned int key = s_key[p];
                if ((key & himask) == prefix)
                    atomicAdd(&s_hist[(key >> (byte * 8)) & 255u], 1u);
            }
            __syncthreads();
            // parallel suffix sum over 256 buckets (threads 0..255 = waves 0..3)
            if (tid < 256) {
                unsigned x = s_hist[tid];
#pragma unroll
                for (int off = 1; off < 64; off <<= 1) {
                    unsigned y = __shfl_down(x, off);
                    if ((tid & 63) + off < 64) x += y;
                }
                s_suf[tid] = x;                      // in-wave inclusive suffix
                if ((tid & 63) == 0) s_wtot[tid >> 6] = x;
            }
            __syncthreads();
            if (tid < 256) {
                unsigned above_w = 0;
                int w = tid >> 6;
                for (int w2 = w + 1; w2 < 4; ++w2) above_w += s_wtot[w2];
                unsigned h    = s_hist[tid];
                unsigned incl = s_suf[tid] + above_w;   // keys in buckets >= tid
                unsigned above = incl - h;              // keys in buckets >  tid
                if ((int)above < rem && rem <= (int)incl) {
                    s_prefix = prefix | ((unsigned)tid << (byte * 8));
                    s_rem = rem - (int)above;
                }
            }
            __syncthreads();
            prefix = s_prefix;
            rem    = s_rem;
        }
    }

    double sum_gt = 0.0;
    int    cnt_gt = 0;
    if (k > 0) {
        for (int p = tid; p < P; p += NT) {
            unsigned int key = s_key[p];
            if (key > prefix) { sum_gt += (double)__uint_as_float(key); ++cnt_gt; }
        }
    }
    for (int off = 32; off; off >>= 1) {
        sum_gt += __shfl_xor(sum_gt, off);
        cnt_gt += __shfl_xor(cnt_gt, off);
    }
    const int wid = tid >> 6;
    if ((tid & 63) == 0) { s_dl[wid] = sum_gt; s_ci[wid] = cnt_gt; }
    __syncthreads();
    if (tid == 0) {
        double sg = 0.0; int cg = 0;
        for (int w = 0; w < NW; ++w) { sg += s_dl[w]; cg += s_ci[w]; }
        double tk = 0.0;
        if (k > 0) tk = sg + (double)(k - cg) * (double)__uint_as_float(prefix);
        loss_c[b] = pos_ce[b] + tk;
    }
}

// ---------- Kernel E: final reduction ----------
__global__ void final_kernel(const double* __restrict__ loss_l,
                             const double* __restrict__ loss_c,
                             const int*    __restrict__ num_pos,
                             float* __restrict__ out)
{
    int t = threadIdx.x; // 64 threads
    double ll = loss_l[t];
    double lc = loss_c[t];
    int    n  = num_pos[t];
    for (int off = 32; off; off >>= 1) {
        ll += __shfl_xor(ll, off);
        lc += __shfl_xor(lc, off);
        n  += __shfl_xor(n, off);
    }
    if (t == 0) {
        double N = (double)n;
        out[0] = (float)(ll / N);
        out[1] = (float)(lc / N);
    }
}

extern "C" void kernel_launch(void* const* d_in, const int* in_sizes, int n_in,
                              void* d_out, int out_size, void* d_ws, size_t ws_size,
                              hipStream_t stream)
{
    const float* loc_data  = (const float*)d_in[0];
    const float* conf_data = (const float*)d_in[1];
    const float* priors    = (const float*)d_in[2];
    const float* truths    = (const float*)d_in[3];
    const int*   labels    = (const int*)d_in[4];
    float* out = (float*)d_out;

    char* ws = (char*)d_ws;
    size_t off = 0;
    float* loss_rank = (float*)(ws + off);             off += (size_t)R_TOTAL * 4;
    unsigned short* cmb = (unsigned short*)(ws + off); off += (size_t)R_TOTAL * 2;
    off = (off + 15) & ~(size_t)15;
    unsigned long long* bpk = (unsigned long long*)(ws + off); off += (size_t)BATCH * M * 8;
    int*    num_pos = (int*)(ws + off);    off += 64 * sizeof(int);
    double* loss_l  = (double*)(ws + off); off += 64 * sizeof(double);
    double* pos_ce  = (double*)(ws + off); off += 64 * sizeof(double);
    double* loss_c  = (double*)(ws + off); off += 64 * sizeof(double);

    // zero bpk + num_pos + loss_l + pos_ce in one async memset (contiguous)
    hipMemsetAsync(bpk, 0,
                   (size_t)BATCH * M * 8 + 64 * sizeof(int) + 2 * 64 * sizeof(double),
                   stream);

    dim3 gA((P + 255) / 256, BATCH);
    prior_match_kernel<<<gA, 256, 0, stream>>>(priors, truths, labels, cmb, bpk);
    force_match_kernel<<<BATCH, 64, 0, stream>>>(bpk, labels, cmb);
    stream_lse_kernel<<<R_TOTAL / RPB, 256, 0, stream>>>(conf_data, loss_rank);
    fixup_kernel<<<R_TOTAL / 256, 256, 0, stream>>>(conf_data, loc_data, priors, truths,
                                                    cmb, loss_rank, loss_l, pos_ce, num_pos);
    topk_kernel<<<BATCH, 1024, 0, stream>>>(loss_rank, num_pos, pos_ce, loss_c);
    final_kernel<<<1, 64, 0, stream>>>(loss_l, loss_c, num_pos, out);
}